// Round 9
// baseline (103.601 us; speedup 1.0000x reference)
//
#include <hip/hip_runtime.h>
#include <float.h>

#define N_SRC 20000
#define N_TAR 20000
#define TPB 256
#define T 8                       // targets per thread
#define TGT_PER_BLK (TPB * T)     // 2048
#define TBLK 10                   // ceil(20000 / 2048)
#define SC 100                    // source chunks; TBLK*SC = 1000 blocks
#define CHUNK 200                 // 100*200 = 20000 exactly
#define FBLOCKS ((N_TAR + TPB - 1) / TPB)   // 79

// q = 0.5*||s||^2 - t.s  so that 0.5*d2 = 0.5*||t||^2 + q.
//
// r8 falsified the AGPR theory (VGPR 32->52, dur unchanged at 2.0x the VALU
// floor). New theory: LDS-latency stall (ds_read_b128 pinned to its consumer
// by the asm wall; VALUBusy overcounted by the gfx94x formula). This version
// removes LDS entirely: source coords are wave-uniform, loaded from global
// (L1-broadcast, chunk is 2.4 KB) in 4-source batches with an A/B software
// pipeline (vmcnt is ordered -> partial waits keep next batch in flight).
// Math: v_min3_f32 folds 2 sources per min: 7 instr / 2 pairs (was 8).

#define DECL(j) \
    const int ti##j = min(tbase + (j) * TPB, N_TAR - 1); \
    const float ntx##j = -tar[ti##j * 3 + 0]; \
    const float nty##j = -tar[ti##j * 3 + 1]; \
    const float ntz##j = -tar[ti##j * 3 + 2]; \
    float m##j = FLT_MAX;

#define LOAD(P, bi) { const float* qp = S + (bi) * 3; \
    sx##P##0 = qp[0];  sy##P##0 = qp[1];  sz##P##0 = qp[2]; \
    sx##P##1 = qp[3];  sy##P##1 = qp[4];  sz##P##1 = qp[5]; \
    sx##P##2 = qp[6];  sy##P##2 = qp[7];  sz##P##2 = qp[8]; \
    sx##P##3 = qp[9];  sy##P##3 = qp[10]; sz##P##3 = qp[11]; }

// 2 sources (a,b) x 1 target j: 6 v_fma + 1 v_min3
#define STEP2(j, P, a, b, wa, wb) { float qa, qb; \
    asm("v_fma_f32 %1, %3, %9, %4\n\t" \
        "v_fma_f32 %2, %6, %9, %7\n\t" \
        "v_fma_f32 %1, %5, %10, %1\n\t" \
        "v_fma_f32 %2, %8, %10, %2\n\t" \
        "v_fma_f32 %1, %11, %12, %1\n\t" \
        "v_fma_f32 %2, %13, %12, %2\n\t" \
        "v_min3_f32 %0, %0, %1, %2" \
        : "+v"(m##j), "=&v"(qa), "=&v"(qb) \
        : "v"(sz##P##a), "v"(wa), "v"(sy##P##a), \
          "v"(sz##P##b), "v"(wb), "v"(sy##P##b), \
          "v"(ntz##j), "v"(nty##j), \
          "v"(sx##P##a), "v"(ntx##j), "v"(sx##P##b)); }

#define COMPUTE(P) { \
    const float w0 = 0.5f*(sx##P##0*sx##P##0 + sy##P##0*sy##P##0 + sz##P##0*sz##P##0); \
    const float w1 = 0.5f*(sx##P##1*sx##P##1 + sy##P##1*sy##P##1 + sz##P##1*sz##P##1); \
    const float w2 = 0.5f*(sx##P##2*sx##P##2 + sy##P##2*sy##P##2 + sz##P##2*sz##P##2); \
    const float w3 = 0.5f*(sx##P##3*sx##P##3 + sy##P##3*sy##P##3 + sz##P##3*sz##P##3); \
    STEP2(0,P,0,1,w0,w1) STEP2(1,P,0,1,w0,w1) STEP2(2,P,0,1,w0,w1) STEP2(3,P,0,1,w0,w1) \
    STEP2(4,P,0,1,w0,w1) STEP2(5,P,0,1,w0,w1) STEP2(6,P,0,1,w0,w1) STEP2(7,P,0,1,w0,w1) \
    STEP2(0,P,2,3,w2,w3) STEP2(1,P,2,3,w2,w3) STEP2(2,P,2,3,w2,w3) STEP2(3,P,2,3,w2,w3) \
    STEP2(4,P,2,3,w2,w3) STEP2(5,P,2,3,w2,w3) STEP2(6,P,2,3,w2,w3) STEP2(7,P,2,3,w2,w3) }

#define STORE(j) \
    { const int t = tbase + (j) * TPB; if (t < N_TAR) part[c * N_TAR + t] = m##j; }

__global__
__attribute__((amdgpu_flat_work_group_size(TPB, TPB)))
__attribute__((amdgpu_waves_per_eu(4, 4)))
void nn_partial_min(
    const float* __restrict__ src, const float* __restrict__ tar,
    float* __restrict__ part, float* __restrict__ out)
{
    if (blockIdx.x == 0 && blockIdx.y == 0 && threadIdx.x == 0) out[0] = 0.f;

    const int c = blockIdx.y;
    const float* S = src + (size_t)c * CHUNK * 3;

    const int tbase = blockIdx.x * TGT_PER_BLK + threadIdx.x;
    DECL(0) DECL(1) DECL(2) DECL(3) DECL(4) DECL(5) DECL(6) DECL(7)

    float sxA0,syA0,szA0, sxA1,syA1,szA1, sxA2,syA2,szA2, sxA3,syA3,szA3;
    float sxB0,syB0,szB0, sxB1,syB1,szB1, sxB2,syB2,szB2, sxB3,syB3,szB3;

    LOAD(A, 0)
#pragma unroll 1
    for (int i = 0; i + 8 <= CHUNK; i += 8) {
        LOAD(B, i + 4)
        COMPUTE(A)
        // prefetch next A (clamped; duplicate sources are harmless under min)
        { const int nx = (i + 8 <= CHUNK - 4) ? (i + 8) : (CHUNK - 4);
          LOAD(A, nx) }
        COMPUTE(B)
    }

    STORE(0) STORE(1) STORE(2) STORE(3) STORE(4) STORE(5) STORE(6) STORE(7)
}

// Kernel 2: combine the SC chunk-mins per target, add 0.5*||t||^2,
// block-reduce, one atomicAdd per block into out[0] (zeroed by kernel 1).
__global__ __launch_bounds__(TPB) void nn_finalize(
    const float* __restrict__ tar, const float* __restrict__ part,
    float* __restrict__ out)
{
    const int t = blockIdx.x * TPB + threadIdx.x;
    float contrib = 0.f;
    if (t < N_TAR) {
        float m = FLT_MAX;
#pragma unroll
        for (int c = 0; c < SC; ++c) m = fminf(m, part[c * N_TAR + t]);
        const float tx = tar[t * 3 + 0];
        const float ty = tar[t * 3 + 1];
        const float tz = tar[t * 3 + 2];
        contrib = 0.5f * (tx * tx + ty * ty + tz * tz) + m;
    }
    for (int off = 32; off > 0; off >>= 1)
        contrib += __shfl_down(contrib, off);
    __shared__ float red[TPB / 64];
    if ((threadIdx.x & 63) == 0) red[threadIdx.x >> 6] = contrib;
    __syncthreads();
    if (threadIdx.x == 0) {
        float s = 0.f;
#pragma unroll
        for (int w = 0; w < TPB / 64; ++w) s += red[w];
        atomicAdd(out, s);
    }
}

extern "C" void kernel_launch(void* const* d_in, const int* in_sizes, int n_in,
                              void* d_out, int out_size, void* d_ws, size_t ws_size,
                              hipStream_t stream) {
    const float* src = (const float*)d_in[0];  // [20000,3] fp32
    const float* tar = (const float*)d_in[1];  // [20000,3] fp32
    float* out = (float*)d_out;                // scalar fp32
    float* part = (float*)d_ws;                // SC * N_TAR floats = 8 MB

    dim3 grid1(TBLK, SC);
    nn_partial_min<<<grid1, TPB, 0, stream>>>(src, tar, part, out);
    nn_finalize<<<FBLOCKS, TPB, 0, stream>>>(tar, part, out);
}

// Round 10
// 99.764 us; speedup vs baseline: 1.0385x; 1.0385x over previous
//
#include <hip/hip_runtime.h>
#include <float.h>

#define N_SRC 20000
#define N_TAR 20000
#define TPB 256
#define T 8                       // targets per thread
#define TGT_PER_BLK (TPB * T)     // 2048
#define TBLK 10                   // ceil(20000 / 2048)
#define SC 100                    // source chunks; TBLK*SC = 1000 blocks
#define CHUNK 200                 // 100*200 = 20000 exactly
#define FBLOCKS ((N_TAR + TPB - 1) / TPB)   // 79

// q = 0.5*||s||^2 - t.s  so that 0.5*d2 = 0.5*||t||^2 + q.
//
// r7-r9 calibration: VALUBusy uses the gfx942 4-cyc formula, real issue was
// ~46% -- the kernel was latency-bound (read-then-use LDS structure, 2-4
// waves/SIMD), not issue-bound. This version software-pipelines the LDS
// reads (register A/B double-buffer, prefetch 4 sources ahead) so ~120 cyc
// of ds_read latency sits behind ~120 issue-cycles of independent asm math,
// and packs 2 sources per min via v_min3_f32 (7 instr / 2 pairs).

#define DECL(j) \
    const int ti##j = min(tbase + (j) * TPB, N_TAR - 1); \
    const float ntx##j = -tar[ti##j * 3 + 0]; \
    const float nty##j = -tar[ti##j * 3 + 1]; \
    const float ntz##j = -tar[ti##j * 3 + 2]; \
    float m##j = FLT_MAX;

// 2 sources (float4 a, b: x,y,z,w=0.5||s||^2) x 1 target j: 6 fma + 1 min3
#define STEP2(j, a, b) { float qa, qb; \
    asm("v_fma_f32 %1, %3, %9, %4\n\t" \
        "v_fma_f32 %2, %6, %9, %7\n\t" \
        "v_fma_f32 %1, %5, %10, %1\n\t" \
        "v_fma_f32 %2, %8, %10, %2\n\t" \
        "v_fma_f32 %1, %11, %12, %1\n\t" \
        "v_fma_f32 %2, %13, %12, %2\n\t" \
        "v_min3_f32 %0, %0, %1, %2" \
        : "+v"(m##j), "=&v"(qa), "=&v"(qb) \
        : "v"((a).z), "v"((a).w), "v"((a).y), \
          "v"((b).z), "v"((b).w), "v"((b).y), \
          "v"(ntz##j), "v"(nty##j), \
          "v"((a).x), "v"(ntx##j), "v"((b).x)); }

#define PAIR(a, b) { \
    STEP2(0, a, b) STEP2(1, a, b) STEP2(2, a, b) STEP2(3, a, b) \
    STEP2(4, a, b) STEP2(5, a, b) STEP2(6, a, b) STEP2(7, a, b) }

#define STORE(j) \
    { const int t = tbase + (j) * TPB; if (t < N_TAR) part[c * N_TAR + t] = m##j; }

__global__
__attribute__((amdgpu_flat_work_group_size(TPB, TPB)))
__attribute__((amdgpu_waves_per_eu(4, 4)))
void nn_partial_min(
    const float* __restrict__ src, const float* __restrict__ tar,
    float* __restrict__ part, float* __restrict__ out)
{
    if (blockIdx.x == 0 && blockIdx.y == 0 && threadIdx.x == 0) out[0] = 0.f;

    __shared__ float4 sh[CHUNK];
    const int c = blockIdx.y;
    const int base = c * CHUNK;
    for (int i = threadIdx.x; i < CHUNK; i += TPB) {
        const int s = base + i;
        if (s < N_SRC) {
            const float x = src[s * 3 + 0];
            const float y = src[s * 3 + 1];
            const float z = src[s * 3 + 2];
            sh[i] = make_float4(x, y, z, 0.5f * (x * x + y * y + z * z));
        }
    }
    __syncthreads();

    const int tbase = blockIdx.x * TGT_PER_BLK + threadIdx.x;
    DECL(0) DECL(1) DECL(2) DECL(3) DECL(4) DECL(5) DECL(6) DECL(7)

    // Software pipeline: compute on (A0,A1)/(B0,B1) while the next four
    // sources are in flight. CHUNK=200: loop i=0..192 step 4 covers
    // sources 0..195 and leaves A=sh[196,197], B=sh[198,199] for the tail.
    float4 A0 = sh[0], A1 = sh[1], B0 = sh[2], B1 = sh[3];
#pragma unroll 1
    for (int i = 0; i + 4 < CHUNK; i += 4) {
        PAIR(A0, A1)
        A0 = sh[i + 4]; A1 = sh[i + 5];
        PAIR(B0, B1)
        B0 = sh[i + 6]; B1 = sh[i + 7];
    }
    PAIR(A0, A1)
    PAIR(B0, B1)

    STORE(0) STORE(1) STORE(2) STORE(3) STORE(4) STORE(5) STORE(6) STORE(7)
}

// Kernel 2: combine the SC chunk-mins per target, add 0.5*||t||^2,
// block-reduce, one atomicAdd per block into out[0] (zeroed by kernel 1).
__global__ __launch_bounds__(TPB) void nn_finalize(
    const float* __restrict__ tar, const float* __restrict__ part,
    float* __restrict__ out)
{
    const int t = blockIdx.x * TPB + threadIdx.x;
    float contrib = 0.f;
    if (t < N_TAR) {
        float m = FLT_MAX;
#pragma unroll
        for (int c = 0; c < SC; ++c) m = fminf(m, part[c * N_TAR + t]);
        const float tx = tar[t * 3 + 0];
        const float ty = tar[t * 3 + 1];
        const float tz = tar[t * 3 + 2];
        contrib = 0.5f * (tx * tx + ty * ty + tz * tz) + m;
    }
    for (int off = 32; off > 0; off >>= 1)
        contrib += __shfl_down(contrib, off);
    __shared__ float red[TPB / 64];
    if ((threadIdx.x & 63) == 0) red[threadIdx.x >> 6] = contrib;
    __syncthreads();
    if (threadIdx.x == 0) {
        float s = 0.f;
#pragma unroll
        for (int w = 0; w < TPB / 64; ++w) s += red[w];
        atomicAdd(out, s);
    }
}

extern "C" void kernel_launch(void* const* d_in, const int* in_sizes, int n_in,
                              void* d_out, int out_size, void* d_ws, size_t ws_size,
                              hipStream_t stream) {
    const float* src = (const float*)d_in[0];  // [20000,3] fp32
    const float* tar = (const float*)d_in[1];  // [20000,3] fp32
    float* out = (float*)d_out;                // scalar fp32
    float* part = (float*)d_ws;                // SC * N_TAR floats = 8 MB

    dim3 grid1(TBLK, SC);
    nn_partial_min<<<grid1, TPB, 0, stream>>>(src, tar, part, out);
    nn_finalize<<<FBLOCKS, TPB, 0, stream>>>(tar, part, out);
}